// Round 4
// baseline (272.994 us; speedup 1.0000x reference)
//
#include <hip/hip_runtime.h>
#include <hip/hip_bf16.h>

#define F 128
#define NG 512

typedef __attribute__((ext_vector_type(8))) short s16x8;
typedef __attribute__((ext_vector_type(4))) float f32x4;

__device__ inline float bf2f(unsigned short u) {
    unsigned int x = ((unsigned int)u) << 16;
    return __builtin_bit_cast(float, x);
}
__device__ inline unsigned short f2bf(float f) {
    __hip_bfloat16 h = __float2bfloat16(f);
    return __builtin_bit_cast(unsigned short, h);
}
__device__ inline float lo16(unsigned int v) { return bf2f((unsigned short)(v & 0xffffu)); }
__device__ inline float hi16(unsigned int v) { return bf2f((unsigned short)(v >> 16)); }
__device__ inline unsigned int pack16(float x, float y) {
    return (unsigned int)f2bf(x) | ((unsigned int)f2bf(y) << 16);
}

// ---------------- cast X f32 -> bf16, row-major (Xr) + per-graph col-major (Xc) ----------------
// block: 256 thr; grid: 64 graphs * 8 node-tiles (64 nodes x 128 feats each)

__global__ __launch_bounds__(256) void cast_kernel(const float* __restrict__ X,
                                                   unsigned short* __restrict__ Xr,
                                                   unsigned short* __restrict__ Xc) {
    __shared__ unsigned short tile[64][F + 4];
    int g = blockIdx.x >> 3;
    int nt = blockIdx.x & 7;
    int node0 = nt * 64;
    int tid = threadIdx.x;
    const float* Xg = X + ((size_t)g * NG + node0) * F;
    unsigned short* Xrg = Xr + ((size_t)g * NG + node0) * F;
    #pragma unroll
    for (int u = tid; u < 64 * 32; u += 256) {
        int row = u >> 5, c4 = u & 31;
        float4 v = ((const float4*)(Xg + (size_t)row * F))[c4];
        unsigned short a0 = f2bf(v.x), a1 = f2bf(v.y), a2 = f2bf(v.z), a3 = f2bf(v.w);
        tile[row][c4 * 4 + 0] = a0;
        tile[row][c4 * 4 + 1] = a1;
        tile[row][c4 * 4 + 2] = a2;
        tile[row][c4 * 4 + 3] = a3;
        uint2 w;
        w.x = (unsigned int)a0 | ((unsigned int)a1 << 16);
        w.y = (unsigned int)a2 | ((unsigned int)a3 << 16);
        ((uint2*)(Xrg + (size_t)row * F))[c4] = w;
    }
    __syncthreads();
    unsigned short* Xcg = Xc + (size_t)g * F * NG;
    #pragma unroll
    for (int u = tid; u < F * 16; u += 256) {
        int f = u >> 4, nb = u & 15;
        int n0 = nb * 4;
        uint2 w;
        w.x = (unsigned int)tile[n0 + 0][f] | ((unsigned int)tile[n0 + 1][f] << 16);
        w.y = (unsigned int)tile[n0 + 2][f] | ((unsigned int)tile[n0 + 3][f] << 16);
        ((uint2*)(Xcg + (size_t)f * NG + node0))[nb] = w;
    }
}

// ---------------- weight prep: W [384][128] f32 -> fragment-contiguous bf16 ----------------

__global__ __launch_bounds__(256) void wprep_kernel(const float* __restrict__ W,
                                                    unsigned short* __restrict__ out) {
    int t = blockIdx.x * 256 + threadIdx.x;
    if (t >= 12 * 8 * 64 * 8) return;
    int j = t & 7;
    int lane = (t >> 3) & 63;
    int ct = (t >> 9) & 7;
    int ks = t >> 12;
    int k = ks * 32 + (lane >> 4) * 8 + j;
    int c = ct * 16 + (lane & 15);
    out[t] = f2bf(W[(size_t)k * F + c]);
}

// ---------------- dense S build ----------------
// cnt: u8 per (g,i,j); scatter edges with packed-byte atomics (dups rare, <255 safe)

__global__ void cnt_scatter_kernel(const int* __restrict__ src, const int* __restrict__ dst,
                                   unsigned int* __restrict__ cnt32, int E) {
    int e = blockIdx.x * blockDim.x + threadIdx.x;
    if (e >= E) return;
    int s = src[e], d = dst[e];
    size_t idx = ((size_t)s << 9) | (unsigned)(d & (NG - 1));
    atomicAdd(&cnt32[idx >> 2], 1u << ((idx & 3) * 8));
}

// Sb[g][i][j] = bf16(alpha*cnt + (i==j)*(1-alpha)); 8 entries per thread

__global__ __launch_bounds__(256) void sgen_kernel(const unsigned char* __restrict__ cnt,
                                                   unsigned short* __restrict__ Sb,
                                                   const float* __restrict__ alphap) {
    size_t t = (size_t)blockIdx.x * 256 + threadIdx.x;
    size_t base = t * 8;
    float alpha = *alphap;
    float diag = 1.0f - alpha;
    int i = (int)((base >> 9) & (NG - 1));
    int j0 = (int)(base & (NG - 1));
    uint2 c = *(const uint2*)(cnt + base);
    unsigned short o[8];
    #pragma unroll
    for (int b = 0; b < 8; ++b) {
        unsigned cv = ((b < 4) ? (c.x >> (8 * b)) : (c.y >> (8 * (b - 4)))) & 0xffu;
        float v = alpha * (float)cv + ((i == j0 + b) ? diag : 0.f);
        o[b] = f2bf(v);
    }
    uint4 w;
    w.x = (unsigned int)o[0] | ((unsigned int)o[1] << 16);
    w.y = (unsigned int)o[2] | ((unsigned int)o[3] << 16);
    w.z = (unsigned int)o[4] | ((unsigned int)o[5] << 16);
    w.w = (unsigned int)o[6] | ((unsigned int)o[7] << 16);
    *(uint4*)(Sb + base) = w;
}

// ---------------- S-apply: C[g] = S[g] @ B[g] via MFMA ----------------
// S row-major [64][512][512]; B col-major [64][128][512].
// grid: 64 graphs x 4 row-tiles; 512 thr = 8 waves x 16 rows.
// Cr: row-major [64][512][128] (nullable); Cc: col-major [64][128][512] (nullable).

__global__ __launch_bounds__(512) void sapply_kernel(
    const unsigned short* __restrict__ S, const unsigned short* __restrict__ Bc,
    unsigned short* __restrict__ Cr, unsigned short* __restrict__ Cc) {
    __shared__ unsigned short smem[128 * F];
    int g = blockIdx.x >> 2;
    int rt = blockIdx.x & 3;
    int tid = threadIdx.x, wave = tid >> 6, lane = tid & 63;
    int lrow = wave * 16 + (lane & 15);
    int ksub = (lane >> 4) * 8;
    const unsigned short* Sg = S + ((size_t)g * NG + rt * 128 + lrow) * NG;
    const unsigned short* Bg = Bc + (size_t)g * F * NG + (size_t)(lane & 15) * NG;

    f32x4 acc[8];
    #pragma unroll
    for (int ct = 0; ct < 8; ++ct) acc[ct] = (f32x4){0.f, 0.f, 0.f, 0.f};

    #pragma unroll 4
    for (int ks = 0; ks < 16; ++ks) {
        s16x8 a = *(const s16x8*)(Sg + ks * 32 + ksub);
        #pragma unroll
        for (int ct = 0; ct < 8; ++ct) {
            s16x8 b = *(const s16x8*)(Bg + (size_t)ct * 16 * NG + ks * 32 + ksub);
            acc[ct] = __builtin_amdgcn_mfma_f32_16x16x32_bf16(a, b, acc[ct], 0, 0, 0);
        }
    }

    int rloc = wave * 16 + ((lane >> 4) << 2);
    if (Cc) {
        unsigned short* Ccg = Cc + (size_t)g * F * NG + rt * 128 + rloc;
        #pragma unroll
        for (int ct = 0; ct < 8; ++ct) {
            int col = ct * 16 + (lane & 15);
            uint2 w;
            w.x = pack16(acc[ct][0], acc[ct][1]);
            w.y = pack16(acc[ct][2], acc[ct][3]);
            *(uint2*)(Ccg + (size_t)col * NG) = w;
        }
    }
    if (Cr) {
        #pragma unroll
        for (int ct = 0; ct < 8; ++ct) {
            int c = ct * 16 + (lane & 15);
            #pragma unroll
            for (int r = 0; r < 4; ++r)
                smem[(size_t)(rloc + r) * F + c] = f2bf(acc[ct][r]);
        }
        __syncthreads();
        uint4* o4 = (uint4*)(Cr + ((size_t)g * NG + rt * 128) * F);
        const uint4* s4 = (const uint4*)smem;
        #pragma unroll
        for (int u = tid; u < 128 * F / 8; u += 512) o4[u] = s4[u];
    }
}

// ---------------- conv via MFMA: out = relu(A0@W0 + A1@W1 + A2@W2 + b) ----------------
// optional col-major dual write (Cc, per-graph [128][512]) for next S-apply.

__global__ __launch_bounds__(512) void conv_mfma_kernel(
    const unsigned short* __restrict__ A0, const unsigned short* __restrict__ A1,
    const unsigned short* __restrict__ A2, const unsigned short* __restrict__ Wswz,
    const float* __restrict__ bias, unsigned short* __restrict__ out,
    unsigned short* __restrict__ Cc) {
    __shared__ unsigned short smem[128 * F];
    int tid = threadIdx.x;
    int wave = tid >> 6;
    int lane = tid & 63;
    int arow = blockIdx.x * 128 + wave * 16 + (lane & 15);
    int asub = (lane >> 4) * 8;

    f32x4 acc[8];
    #pragma unroll
    for (int ct = 0; ct < 8; ++ct) acc[ct] = (f32x4){0.f, 0.f, 0.f, 0.f};

    const unsigned short* mats[3] = {A0, A1, A2};
    #pragma unroll
    for (int ks = 0; ks < 12; ++ks) {
        const unsigned short* Ab = mats[ks >> 2];
        int kk = ks & 3;
        s16x8 a = *(const s16x8*)(Ab + (size_t)arow * F + kk * 32 + asub);
        const unsigned short* wb = Wswz + ((size_t)ks * 8 * 64 + lane) * 8;
        #pragma unroll
        for (int ct = 0; ct < 8; ++ct) {
            s16x8 b = *(const s16x8*)(wb + (size_t)ct * 64 * 8);
            acc[ct] = __builtin_amdgcn_mfma_f32_16x16x32_bf16(a, b, acc[ct], 0, 0, 0);
        }
    }

    int rloc = wave * 16 + ((lane >> 4) << 2);
    int g = blockIdx.x >> 2;
    int node0 = (blockIdx.x & 3) * 128 + rloc;
    #pragma unroll
    for (int ct = 0; ct < 8; ++ct) {
        int c = ct * 16 + (lane & 15);
        float b = bias[c];
        float v0 = fmaxf(acc[ct][0] + b, 0.f);
        float v1 = fmaxf(acc[ct][1] + b, 0.f);
        float v2 = fmaxf(acc[ct][2] + b, 0.f);
        float v3 = fmaxf(acc[ct][3] + b, 0.f);
        smem[(size_t)(rloc + 0) * F + c] = f2bf(v0);
        smem[(size_t)(rloc + 1) * F + c] = f2bf(v1);
        smem[(size_t)(rloc + 2) * F + c] = f2bf(v2);
        smem[(size_t)(rloc + 3) * F + c] = f2bf(v3);
        if (Cc) {
            uint2 w;
            w.x = pack16(v0, v1);
            w.y = pack16(v2, v3);
            *(uint2*)(Cc + (size_t)g * F * NG + (size_t)c * NG + node0) = w;
        }
    }
    __syncthreads();
    const uint4* s4 = (const uint4*)smem;
    uint4* o4 = (uint4*)(out + (size_t)blockIdx.x * 128 * F);
    #pragma unroll
    for (int u = tid; u < 128 * F / 8; u += 512) o4[u] = s4[u];
}

// ---------------- max pool over nodes per graph (bf16 in, f32 out) ----------------

__global__ __launch_bounds__(512) void maxpool_kernel(const unsigned short* __restrict__ H,
                                                      float* __restrict__ pooled) {
    __shared__ float redx[512];
    __shared__ float redy[512];
    int b = blockIdx.x;
    int c = threadIdx.x & 63;
    int q = threadIdx.x >> 6;
    const unsigned int* base = (const unsigned int*)(H + (size_t)b * NG * F);
    float mx = -3.402823466e38f, my = -3.402823466e38f;
    for (int i = q * 64; i < q * 64 + 64; ++i) {
        unsigned int v = base[(size_t)i * 64 + c];
        mx = fmaxf(mx, lo16(v));
        my = fmaxf(my, hi16(v));
    }
    redx[threadIdx.x] = mx;
    redy[threadIdx.x] = my;
    __syncthreads();
    if (q == 0) {
        #pragma unroll
        for (int gq = 1; gq < 8; ++gq) {
            mx = fmaxf(mx, redx[gq * 64 + c]);
            my = fmaxf(my, redy[gq * 64 + c]);
        }
        pooled[(size_t)b * F + 2 * c] = mx;
        pooled[(size_t)b * F + 2 * c + 1] = my;
    }
}

// ---------------- output head: out = pooled @ Wout + bout (f32) ----------------

__global__ __launch_bounds__(64) void out_gemm_kernel(const float* __restrict__ pooled,
                                                      const float* __restrict__ Wout,
                                                      const float* __restrict__ bout,
                                                      float* __restrict__ out) {
    __shared__ float p[F];
    int b = blockIdx.x, g = threadIdx.x;
    p[g] = pooled[(size_t)b * F + g];
    p[g + 64] = pooled[(size_t)b * F + g + 64];
    __syncthreads();
    float acc = bout[g];
    #pragma unroll 8
    for (int k = 0; k < F; ++k) acc += p[k] * Wout[k * 64 + g];
    out[(size_t)b * 64 + g] = acc;
}

// ---------------- launch ----------------

extern "C" void kernel_launch(void* const* d_in, const int* in_sizes, int n_in,
                              void* d_out, int out_size, void* d_ws, size_t ws_size,
                              hipStream_t stream) {
    const float* X     = (const float*)d_in[0];
    const int*   ei    = (const int*)d_in[2];
    const float* W1    = (const float*)d_in[3];
    const float* b1    = (const float*)d_in[4];
    const float* W2    = (const float*)d_in[5];
    const float* b2    = (const float*)d_in[6];
    const float* Wout  = (const float*)d_in[7];
    const float* bout  = (const float*)d_in[8];
    const float* alpha = (const float*)d_in[9];

    const int N = in_sizes[0] / F;   // 32768
    const int E = in_sizes[2] / 2;   // 524288
    const int Bg = N / NG;           // 64

    const int* srcv = ei;
    const int* dstv = ei + E;

    char* ws = (char*)d_ws;
    const size_t SBYTES = (size_t)Bg * NG * NG * 2;   // 33.55 MB
    const size_t PBYTES = (size_t)N * F * 2;          // 8.39 MB each

    unsigned short* Sb = (unsigned short*)ws;
    unsigned short* P0 = (unsigned short*)(ws + SBYTES);               // Xr -> h1r -> h2r
    unsigned short* P1 = (unsigned short*)(ws + SBYTES + PBYTES);      // Xc -> h1c
    unsigned short* P2 = (unsigned short*)(ws + SBYTES + 2 * PBYTES);  // t1r / u1r
    unsigned short* P3 = (unsigned short*)(ws + SBYTES + 3 * PBYTES);  // t1c / u1c
    unsigned short* P4 = (unsigned short*)(ws + SBYTES + 4 * PBYTES);  // t2r / u2r
    char* tail = ws + SBYTES + 5 * PBYTES;
    unsigned short* Wswz1 = (unsigned short*)tail;
    unsigned short* Wswz2 = Wswz1 + (size_t)3 * F * F;
    float* pooled = (float*)(Wswz2 + (size_t)3 * F * F);
    // cnt aliases P2+P3 (exactly 16.78 MB); consumed by sgen before apply1 writes P2/P3
    unsigned int* cnt32 = (unsigned int*)P2;

    // prep
    cast_kernel<<<Bg * 8, 256, 0, stream>>>(X, P0, P1);
    wprep_kernel<<<192, 256, 0, stream>>>(W1, Wswz1);
    wprep_kernel<<<192, 256, 0, stream>>>(W2, Wswz2);

    // dense S build
    hipMemsetAsync(cnt32, 0, (size_t)Bg * NG * NG, stream);
    cnt_scatter_kernel<<<(E + 255) / 256, 256, 0, stream>>>(srcv, dstv, cnt32, E);
    sgen_kernel<<<(Bg * NG * NG / 8) / 256, 256, 0, stream>>>((const unsigned char*)cnt32, Sb, alpha);

    // layer 1
    sapply_kernel<<<Bg * 4, 512, 0, stream>>>(Sb, P1, P2, P3);          // t1 = S@X   (row+col)
    sapply_kernel<<<Bg * 4, 512, 0, stream>>>(Sb, P3, P4, nullptr);     // t2 = S@t1  (row)
    conv_mfma_kernel<<<N / 128, 512, 0, stream>>>(P0, P2, P4, Wswz1, b1, P0, P1);  // h1 (row->P0, col->P1)

    // layer 2
    sapply_kernel<<<Bg * 4, 512, 0, stream>>>(Sb, P1, P2, P3);          // u1 = S@h1
    sapply_kernel<<<Bg * 4, 512, 0, stream>>>(Sb, P3, P4, nullptr);     // u2 = S@u1
    conv_mfma_kernel<<<N / 128, 512, 0, stream>>>(P0, P2, P4, Wswz2, b2, P0, nullptr);  // h2 -> P0

    // head
    maxpool_kernel<<<Bg, 512, 0, stream>>>(P0, pooled);
    out_gemm_kernel<<<Bg, 64, 0, stream>>>(pooled, Wout, bout, (float*)d_out);
}

// Round 5
// 227.240 us; speedup vs baseline: 1.2013x; 1.2013x over previous
//
#include <hip/hip_runtime.h>
#include <hip/hip_bf16.h>

#define F 128
#define NG 512

typedef __attribute__((ext_vector_type(8))) short s16x8;
typedef __attribute__((ext_vector_type(4))) float f32x4;

__device__ inline float bf2f(unsigned short u) {
    unsigned int x = ((unsigned int)u) << 16;
    return __builtin_bit_cast(float, x);
}
__device__ inline unsigned short f2bf(float f) {
    __hip_bfloat16 h = __float2bfloat16(f);
    return __builtin_bit_cast(unsigned short, h);
}
__device__ inline unsigned int pack16(float x, float y) {
    return (unsigned int)f2bf(x) | ((unsigned int)f2bf(y) << 16);
}

// ---------------- cast X f32 -> bf16 row-major (Xr) + per-graph col-major (Xc) ----------------

__global__ __launch_bounds__(256) void cast_kernel(const float* __restrict__ X,
                                                   unsigned short* __restrict__ Xr,
                                                   unsigned short* __restrict__ Xc) {
    __shared__ unsigned short tile[64][F + 4];
    int g = blockIdx.x >> 3;
    int nt = blockIdx.x & 7;
    int node0 = nt * 64;
    int tid = threadIdx.x;
    const float* Xg = X + ((size_t)g * NG + node0) * F;
    unsigned short* Xrg = Xr + ((size_t)g * NG + node0) * F;
    #pragma unroll
    for (int u = tid; u < 64 * 32; u += 256) {
        int row = u >> 5, c4 = u & 31;
        float4 v = ((const float4*)(Xg + (size_t)row * F))[c4];
        unsigned short a0 = f2bf(v.x), a1 = f2bf(v.y), a2 = f2bf(v.z), a3 = f2bf(v.w);
        tile[row][c4 * 4 + 0] = a0;
        tile[row][c4 * 4 + 1] = a1;
        tile[row][c4 * 4 + 2] = a2;
        tile[row][c4 * 4 + 3] = a3;
        uint2 w;
        w.x = (unsigned int)a0 | ((unsigned int)a1 << 16);
        w.y = (unsigned int)a2 | ((unsigned int)a3 << 16);
        ((uint2*)(Xrg + (size_t)row * F))[c4] = w;
    }
    __syncthreads();
    unsigned short* Xcg = Xc + (size_t)g * F * NG;
    #pragma unroll
    for (int u = tid; u < F * 16; u += 256) {
        int f = u >> 4, nb = u & 15;
        int n0 = nb * 4;
        uint2 w;
        w.x = (unsigned int)tile[n0 + 0][f] | ((unsigned int)tile[n0 + 1][f] << 16);
        w.y = (unsigned int)tile[n0 + 2][f] | ((unsigned int)tile[n0 + 3][f] << 16);
        ((uint2*)(Xcg + (size_t)f * NG + node0))[nb] = w;
    }
}

// ---------------- weight prep: W [384][128] f32 -> fragment-contiguous bf16 ----------------
// Wswz[ks][ct][lane][j] = bf16(W[ks*32 + (lane>>4)*8 + j][ct*16 + (lane&15)])

__global__ __launch_bounds__(256) void wprep_kernel(const float* __restrict__ W,
                                                    unsigned short* __restrict__ out) {
    int t = blockIdx.x * 256 + threadIdx.x;
    if (t >= 12 * 8 * 64 * 8) return;
    int j = t & 7;
    int lane = (t >> 3) & 63;
    int ct = (t >> 9) & 7;
    int ks = t >> 12;
    int k = ks * 32 + (lane >> 4) * 8 + j;
    int c = ct * 16 + (lane & 15);
    out[t] = f2bf(W[(size_t)k * F + c]);
}

// ---------------- dense S build ----------------

__global__ void cnt_scatter_kernel(const int* __restrict__ src, const int* __restrict__ dst,
                                   unsigned int* __restrict__ cnt32, int E) {
    int e = blockIdx.x * blockDim.x + threadIdx.x;
    if (e >= E) return;
    int s = src[e], d = dst[e];
    size_t idx = ((size_t)s << 9) | (unsigned)(d & (NG - 1));
    atomicAdd(&cnt32[idx >> 2], 1u << ((idx & 3) * 8));
}

__global__ __launch_bounds__(256) void sgen_kernel(const unsigned char* __restrict__ cnt,
                                                   unsigned short* __restrict__ Sb,
                                                   const float* __restrict__ alphap) {
    size_t t = (size_t)blockIdx.x * 256 + threadIdx.x;
    size_t base = t * 8;
    float alpha = *alphap;
    float diag = 1.0f - alpha;
    int i = (int)((base >> 9) & (NG - 1));
    int j0 = (int)(base & (NG - 1));
    uint2 c = *(const uint2*)(cnt + base);
    unsigned short o[8];
    #pragma unroll
    for (int b = 0; b < 8; ++b) {
        unsigned cv = ((b < 4) ? (c.x >> (8 * b)) : (c.y >> (8 * (b - 4)))) & 0xffu;
        float v = alpha * (float)cv + ((i == j0 + b) ? diag : 0.f);
        o[b] = f2bf(v);
    }
    uint4 w;
    w.x = (unsigned int)o[0] | ((unsigned int)o[1] << 16);
    w.y = (unsigned int)o[2] | ((unsigned int)o[3] << 16);
    w.z = (unsigned int)o[4] | ((unsigned int)o[5] << 16);
    w.w = (unsigned int)o[6] | ((unsigned int)o[7] << 16);
    *(uint4*)(Sb + base) = w;
}

// ---------------- S-apply: C[g] = S[g] @ B[g], writes row-major Cr + col-major Cc ----------------

__global__ __launch_bounds__(512) void sapply_kernel(
    const unsigned short* __restrict__ S, const unsigned short* __restrict__ Bc,
    unsigned short* __restrict__ Cr, unsigned short* __restrict__ Cc) {
    __shared__ unsigned short smem[128 * F];
    int g = blockIdx.x >> 2;
    int rt = blockIdx.x & 3;
    int tid = threadIdx.x, wave = tid >> 6, lane = tid & 63;
    int lrow = wave * 16 + (lane & 15);
    int ksub = (lane >> 4) * 8;
    const unsigned short* Sg = S + ((size_t)g * NG + rt * 128 + lrow) * NG;
    const unsigned short* Bg = Bc + (size_t)g * F * NG + (size_t)(lane & 15) * NG;

    f32x4 acc[8];
    #pragma unroll
    for (int ct = 0; ct < 8; ++ct) acc[ct] = (f32x4){0.f, 0.f, 0.f, 0.f};

    #pragma unroll 4
    for (int ks = 0; ks < 16; ++ks) {
        s16x8 a = *(const s16x8*)(Sg + ks * 32 + ksub);
        #pragma unroll
        for (int ct = 0; ct < 8; ++ct) {
            s16x8 b = *(const s16x8*)(Bg + (size_t)ct * 16 * NG + ks * 32 + ksub);
            acc[ct] = __builtin_amdgcn_mfma_f32_16x16x32_bf16(a, b, acc[ct], 0, 0, 0);
        }
    }

    int rloc = wave * 16 + ((lane >> 4) << 2);
    unsigned short* Ccg = Cc + (size_t)g * F * NG + rt * 128 + rloc;
    #pragma unroll
    for (int ct = 0; ct < 8; ++ct) {
        int col = ct * 16 + (lane & 15);
        uint2 w;
        w.x = pack16(acc[ct][0], acc[ct][1]);
        w.y = pack16(acc[ct][2], acc[ct][3]);
        *(uint2*)(Ccg + (size_t)col * NG) = w;
        #pragma unroll
        for (int r = 0; r < 4; ++r)
            smem[(size_t)(rloc + r) * F + col] = f2bf(acc[ct][r]);
    }
    __syncthreads();
    uint4* o4 = (uint4*)(Cr + ((size_t)g * NG + rt * 128) * F);
    const uint4* s4 = (const uint4*)smem;
    #pragma unroll
    for (int u = tid; u < 128 * F / 8; u += 512) o4[u] = s4[u];
}

// ---------------- fused: t2 = S@Bc (MFMA) -> LDS(swizzled) -> h = relu(A0@W0 + A1@W1 + t2@W2 + b) ----
// WRITE_H=1: write h row-major (Hr) + col-major (Hc). WRITE_H=0: per-column max -> atomicMax(pooled).

template <int WRITE_H>
__global__ __launch_bounds__(512) void fused_conv_kernel(
    const unsigned short* __restrict__ S, const unsigned short* __restrict__ Bc,
    const unsigned short* __restrict__ A0, const unsigned short* __restrict__ A1,
    const unsigned short* __restrict__ Wswz, const float* __restrict__ bias,
    unsigned short* __restrict__ Hr, unsigned short* __restrict__ Hc,
    float* __restrict__ pooled) {
    __shared__ unsigned short smem[128 * F];
    const int g = blockIdx.x >> 2;
    const int rt = blockIdx.x & 3;
    const int tid = threadIdx.x, wave = tid >> 6, lane = tid & 63;
    const int l15 = lane & 15;
    const int ksub = (lane >> 4) * 8;
    const int lrow = wave * 16 + l15;

    // ---- S-phase: t2 tile = S(rows of this tile) @ Bc ----
    {
        const unsigned short* Sg = S + ((size_t)g * NG + rt * 128 + lrow) * NG;
        const unsigned short* Bg = Bc + (size_t)g * F * NG + (size_t)l15 * NG;
        f32x4 acc[8];
        #pragma unroll
        for (int ct = 0; ct < 8; ++ct) acc[ct] = (f32x4){0.f, 0.f, 0.f, 0.f};
        #pragma unroll 4
        for (int ks = 0; ks < 16; ++ks) {
            s16x8 a = *(const s16x8*)(Sg + ks * 32 + ksub);
            #pragma unroll
            for (int ct = 0; ct < 8; ++ct) {
                s16x8 b = *(const s16x8*)(Bg + (size_t)ct * 16 * NG + ks * 32 + ksub);
                acc[ct] = __builtin_amdgcn_mfma_f32_16x16x32_bf16(a, b, acc[ct], 0, 0, 0);
            }
        }
        // stage t2 to LDS, XOR-swizzled in 8-elem chunks: elem = row*128 + ((col>>3)^(row&15))*8 + (col&7)
        int rloc = wave * 16 + ((lane >> 4) << 2);
        #pragma unroll
        for (int ct = 0; ct < 8; ++ct) {
            int col = ct * 16 + l15;
            #pragma unroll
            for (int r = 0; r < 4; ++r) {
                int row = rloc + r;
                smem[row * F + ((((col >> 3) ^ (row & 15)) << 3) | (col & 7))] = f2bf(acc[ct][r]);
            }
        }
    }
    __syncthreads();

    // ---- conv phase: h = A0@W0 + A1@W1 + t2@W2 ----
    f32x4 acc[8];
    #pragma unroll
    for (int ct = 0; ct < 8; ++ct) acc[ct] = (f32x4){0.f, 0.f, 0.f, 0.f};
    const int arow = blockIdx.x * 128 + lrow;
    #pragma unroll
    for (int ks = 0; ks < 12; ++ks) {
        s16x8 a;
        if (ks < 8) {
            const unsigned short* Ab = (ks < 4) ? A0 : A1;
            int kk = ks & 3;
            a = *(const s16x8*)(Ab + (size_t)arow * F + kk * 32 + ksub);
        } else {
            int kk = ks - 8;
            int c8 = kk * 4 + (lane >> 4);
            a = *(const s16x8*)(smem + lrow * F + ((c8 ^ (lrow & 15)) << 3));
        }
        const unsigned short* wb = Wswz + ((size_t)ks * 8 * 64 + lane) * 8;
        #pragma unroll
        for (int ct = 0; ct < 8; ++ct) {
            s16x8 b = *(const s16x8*)(wb + (size_t)ct * 64 * 8);
            acc[ct] = __builtin_amdgcn_mfma_f32_16x16x32_bf16(a, b, acc[ct], 0, 0, 0);
        }
    }
    __syncthreads();   // all LDS A-frag reads done; smem reusable

    const int rloc = wave * 16 + ((lane >> 4) << 2);
    if (WRITE_H) {
        // bias+relu; direct col-major store + LDS-staged row-major store
        #pragma unroll
        for (int ct = 0; ct < 8; ++ct) {
            int col = ct * 16 + l15;
            float b = bias[col];
            float v0 = fmaxf(acc[ct][0] + b, 0.f);
            float v1 = fmaxf(acc[ct][1] + b, 0.f);
            float v2 = fmaxf(acc[ct][2] + b, 0.f);
            float v3 = fmaxf(acc[ct][3] + b, 0.f);
            uint2 w;
            w.x = pack16(v0, v1);
            w.y = pack16(v2, v3);
            *(uint2*)(Hc + (size_t)g * F * NG + (size_t)col * NG + rt * 128 + rloc) = w;
            smem[(rloc + 0) * F + col] = f2bf(v0);
            smem[(rloc + 1) * F + col] = f2bf(v1);
            smem[(rloc + 2) * F + col] = f2bf(v2);
            smem[(rloc + 3) * F + col] = f2bf(v3);
        }
        __syncthreads();
        uint4* o4 = (uint4*)(Hr + (size_t)blockIdx.x * 128 * F);
        const uint4* s4 = (const uint4*)smem;
        #pragma unroll
        for (int u = tid; u < 128 * F / 8; u += 512) o4[u] = s4[u];
    } else {
        // bias+relu; column-max over this block's 128 rows -> atomicMax into pooled[g][col]
        float* wmax = (float*)smem;   // [8 waves][128 cols]
        #pragma unroll
        for (int ct = 0; ct < 8; ++ct) {
            int col = ct * 16 + l15;
            float b = bias[col];
            float m = fmaxf(fmaxf(acc[ct][0], acc[ct][1]), fmaxf(acc[ct][2], acc[ct][3]));
            m = fmaxf(m + b, 0.f);
            m = fmaxf(m, __shfl_xor(m, 16));
            m = fmaxf(m, __shfl_xor(m, 32));
            if (lane < 16) wmax[wave * F + col] = m;
        }
        __syncthreads();
        if (tid < F) {
            float m = wmax[tid];
            #pragma unroll
            for (int w = 1; w < 8; ++w) m = fmaxf(m, wmax[w * F + tid]);
            atomicMax((unsigned int*)(pooled + (size_t)g * F + tid), __float_as_uint(m));
        }
    }
}

// ---------------- output head: out = pooled @ Wout + bout (f32) ----------------

__global__ __launch_bounds__(64) void out_gemm_kernel(const float* __restrict__ pooled,
                                                      const float* __restrict__ Wout,
                                                      const float* __restrict__ bout,
                                                      float* __restrict__ out) {
    __shared__ float p[F];
    int b = blockIdx.x, g = threadIdx.x;
    p[g] = pooled[(size_t)b * F + g];
    p[g + 64] = pooled[(size_t)b * F + g + 64];
    __syncthreads();
    float acc = bout[g];
    #pragma unroll 8
    for (int k = 0; k < F; ++k) acc += p[k] * Wout[k * 64 + g];
    out[(size_t)b * 64 + g] = acc;
}

// ---------------- launch ----------------

extern "C" void kernel_launch(void* const* d_in, const int* in_sizes, int n_in,
                              void* d_out, int out_size, void* d_ws, size_t ws_size,
                              hipStream_t stream) {
    const float* X     = (const float*)d_in[0];
    const int*   ei    = (const int*)d_in[2];
    const float* W1    = (const float*)d_in[3];
    const float* b1    = (const float*)d_in[4];
    const float* W2    = (const float*)d_in[5];
    const float* b2    = (const float*)d_in[6];
    const float* Wout  = (const float*)d_in[7];
    const float* bout  = (const float*)d_in[8];
    const float* alpha = (const float*)d_in[9];

    const int N = in_sizes[0] / F;   // 32768
    const int E = in_sizes[2] / 2;   // 524288
    const int Bg = N / NG;           // 64

    const int* srcv = ei;
    const int* dstv = ei + E;

    char* ws = (char*)d_ws;
    const size_t SBYTES = (size_t)Bg * NG * NG * 2;   // 33.55 MB
    const size_t PBYTES = (size_t)N * F * 2;          // 8.39 MB each

    unsigned short* Sb = (unsigned short*)ws;
    unsigned short* P0 = (unsigned short*)(ws + SBYTES);               // Xr -> h1r
    unsigned short* P1 = (unsigned short*)(ws + SBYTES + PBYTES);      // Xc -> h1c
    unsigned short* P2 = (unsigned short*)(ws + SBYTES + 2 * PBYTES);  // t1r / u1r
    unsigned short* P3 = (unsigned short*)(ws + SBYTES + 3 * PBYTES);  // t1c / u1c
    char* tail = ws + SBYTES + 4 * PBYTES;
    unsigned short* Wswz1 = (unsigned short*)tail;
    unsigned short* Wswz2 = Wswz1 + (size_t)3 * F * F;
    float* pooled = (float*)(Wswz2 + (size_t)3 * F * F);
    // cnt aliases P2+P3 (exactly 16.78 MB); consumed by sgen before sapply writes P2/P3
    unsigned int* cnt32 = (unsigned int*)P2;

    // prep
    cast_kernel<<<Bg * 8, 256, 0, stream>>>(X, P0, P1);
    wprep_kernel<<<192, 256, 0, stream>>>(W1, Wswz1);
    wprep_kernel<<<192, 256, 0, stream>>>(W2, Wswz2);

    // dense S build + pooled init (relu >= 0, so 0 is a valid max identity)
    hipMemsetAsync(cnt32, 0, (size_t)Bg * NG * NG, stream);
    hipMemsetAsync(pooled, 0, (size_t)Bg * F * 4, stream);
    cnt_scatter_kernel<<<(E + 255) / 256, 256, 0, stream>>>(srcv, dstv, cnt32, E);
    sgen_kernel<<<(Bg * NG * NG / 8) / 256, 256, 0, stream>>>((const unsigned char*)cnt32, Sb, alpha);

    // layer 1: t1 = S@X; h1 = relu(X@W0 + t1@W1 + (S@t1)@W2 + b1)
    sapply_kernel<<<Bg * 4, 512, 0, stream>>>(Sb, P1, P2, P3);
    fused_conv_kernel<1><<<Bg * 4, 512, 0, stream>>>(Sb, P3, P0, P2, Wswz1, b1, P0, P1, nullptr);

    // layer 2: u1 = S@h1; pooled = colmax(relu(h1@W0 + u1@W1 + (S@u1)@W2 + b2))
    sapply_kernel<<<Bg * 4, 512, 0, stream>>>(Sb, P1, P2, P3);
    fused_conv_kernel<0><<<Bg * 4, 512, 0, stream>>>(Sb, P3, P0, P2, Wswz2, b2, nullptr, nullptr, pooled);

    // head
    out_gemm_kernel<<<Bg, 64, 0, stream>>>(pooled, Wout, bout, (float*)d_out);
}

// Round 6
// 142.762 us; speedup vs baseline: 1.9122x; 1.5917x over previous
//
#include <hip/hip_runtime.h>
#include <hip/hip_bf16.h>

#define F 128
#define NG 512

typedef __attribute__((ext_vector_type(8))) short s16x8;
typedef __attribute__((ext_vector_type(4))) float f32x4;

__device__ inline float bf2f(unsigned short u) {
    unsigned int x = ((unsigned int)u) << 16;
    return __builtin_bit_cast(float, x);
}
__device__ inline unsigned short f2bf(float f) {
    __hip_bfloat16 h = __float2bfloat16(f);
    return __builtin_bit_cast(unsigned short, h);
}
__device__ inline unsigned int pack16(float x, float y) {
    return (unsigned int)f2bf(x) | ((unsigned int)f2bf(y) << 16);
}

// ---------------- cast X f32 -> bf16 row-major (Xr) + per-graph col-major (Xc) ----------------

__global__ __launch_bounds__(256) void cast_kernel(const float* __restrict__ X,
                                                   unsigned short* __restrict__ Xr,
                                                   unsigned short* __restrict__ Xc) {
    __shared__ unsigned short tile[64][F + 4];
    int g = blockIdx.x >> 3;
    int nt = blockIdx.x & 7;
    int node0 = nt * 64;
    int tid = threadIdx.x;
    const float* Xg = X + ((size_t)g * NG + node0) * F;
    unsigned short* Xrg = Xr + ((size_t)g * NG + node0) * F;
    #pragma unroll
    for (int u = tid; u < 64 * 32; u += 256) {
        int row = u >> 5, c4 = u & 31;
        float4 v = ((const float4*)(Xg + (size_t)row * F))[c4];
        unsigned short a0 = f2bf(v.x), a1 = f2bf(v.y), a2 = f2bf(v.z), a3 = f2bf(v.w);
        tile[row][c4 * 4 + 0] = a0;
        tile[row][c4 * 4 + 1] = a1;
        tile[row][c4 * 4 + 2] = a2;
        tile[row][c4 * 4 + 3] = a3;
        uint2 w;
        w.x = (unsigned int)a0 | ((unsigned int)a1 << 16);
        w.y = (unsigned int)a2 | ((unsigned int)a3 << 16);
        ((uint2*)(Xrg + (size_t)row * F))[c4] = w;
    }
    __syncthreads();
    unsigned short* Xcg = Xc + (size_t)g * F * NG;
    #pragma unroll
    for (int u = tid; u < F * 16; u += 256) {
        int f = u >> 4, nb = u & 15;
        int n0 = nb * 4;
        uint2 w;
        w.x = (unsigned int)tile[n0 + 0][f] | ((unsigned int)tile[n0 + 1][f] << 16);
        w.y = (unsigned int)tile[n0 + 2][f] | ((unsigned int)tile[n0 + 3][f] << 16);
        ((uint2*)(Xcg + (size_t)f * NG + node0))[nb] = w;
    }
}

// ---------------- weight prep (both layers): W [384][128] f32 -> fragment-contiguous bf16 ----

__global__ __launch_bounds__(256) void wprep_kernel(const float* __restrict__ W1,
                                                    const float* __restrict__ W2,
                                                    unsigned short* __restrict__ o1,
                                                    unsigned short* __restrict__ o2) {
    int t = blockIdx.x * 256 + threadIdx.x;
    const float* W = (t < 49152) ? W1 : W2;
    unsigned short* o = (t < 49152) ? o1 : o2;
    int tt = (t < 49152) ? t : t - 49152;
    int j = tt & 7;
    int lane = (tt >> 3) & 63;
    int ct = (tt >> 9) & 7;
    int ks = tt >> 12;
    int k = ks * 32 + (lane >> 4) * 8 + j;
    int c = ct * 16 + (lane & 15);
    o[tt] = f2bf(W[(size_t)k * F + c]);
}

// ---------------- dense S build ----------------

__global__ void cnt_scatter_kernel(const int* __restrict__ src, const int* __restrict__ dst,
                                   unsigned int* __restrict__ cnt32, int E) {
    int e = blockIdx.x * blockDim.x + threadIdx.x;
    if (e >= E) return;
    int s = src[e], d = dst[e];
    size_t idx = ((size_t)s << 9) | (unsigned)(d & (NG - 1));
    atomicAdd(&cnt32[idx >> 2], 1u << ((idx & 3) * 8));
}

__global__ __launch_bounds__(256) void sgen_kernel(const unsigned char* __restrict__ cnt,
                                                   unsigned short* __restrict__ Sb,
                                                   const float* __restrict__ alphap) {
    size_t t = (size_t)blockIdx.x * 256 + threadIdx.x;
    size_t base = t * 8;
    float alpha = *alphap;
    float diag = 1.0f - alpha;
    int i = (int)((base >> 9) & (NG - 1));
    int j0 = (int)(base & (NG - 1));
    uint2 c = *(const uint2*)(cnt + base);
    unsigned short o[8];
    #pragma unroll
    for (int b = 0; b < 8; ++b) {
        unsigned cv = ((b < 4) ? (c.x >> (8 * b)) : (c.y >> (8 * (b - 4)))) & 0xffu;
        float v = alpha * (float)cv + ((i == j0 + b) ? diag : 0.f);
        o[b] = f2bf(v);
    }
    uint4 w;
    w.x = (unsigned int)o[0] | ((unsigned int)o[1] << 16);
    w.y = (unsigned int)o[2] | ((unsigned int)o[3] << 16);
    w.z = (unsigned int)o[4] | ((unsigned int)o[5] << 16);
    w.w = (unsigned int)o[6] | ((unsigned int)o[7] << 16);
    *(uint4*)(Sb + base) = w;
}

// ---------------- S-apply with B staged in LDS: C[g] = S[g] @ B[g] ----------------
// B element [k][col] lives at Bs[col*512 + ((k>>3)^(col&7))*8 + (k&7)]  (chunk XOR swizzle).
// Epilogue: direct col-major store + LDS-staged row-major store (reuses Bs).

__global__ __launch_bounds__(512) void sapply_kernel(
    const unsigned short* __restrict__ S, const unsigned short* __restrict__ Bc,
    unsigned short* __restrict__ Cr, unsigned short* __restrict__ Cc) {
    __shared__ unsigned short Bs[65536];   // 128 KB
    const int g = blockIdx.x >> 2, rt = blockIdx.x & 3;
    const int tid = threadIdx.x, wave = tid >> 6, lane = tid & 63;
    const int l15 = lane & 15, hi = lane >> 4;
    const int lrow = wave * 16 + l15;

    const unsigned short* Bcg = Bc + (size_t)g * F * NG;
    #pragma unroll
    for (int it = 0; it < 16; ++it) {
        int u = it * 512 + tid;
        int f = u >> 6, c = u & 63;
        *(uint4*)(Bs + f * 512 + ((c ^ (f & 7)) << 3)) =
            *(const uint4*)(Bcg + (size_t)f * NG + (c << 3));
    }
    __syncthreads();

    f32x4 acc[8];
    #pragma unroll
    for (int ct = 0; ct < 8; ++ct) acc[ct] = (f32x4){0.f, 0.f, 0.f, 0.f};

    const unsigned short* Sg = S + ((size_t)g * NG + rt * 128 + lrow) * NG;
    const int bxor = l15 & 7;
    #pragma unroll 4
    for (int ks = 0; ks < 16; ++ks) {
        s16x8 a = *(const s16x8*)(Sg + ks * 32 + hi * 8);
        #pragma unroll
        for (int ct = 0; ct < 8; ++ct) {
            int col = ct * 16 + l15;
            s16x8 b = *(const s16x8*)(Bs + col * 512 + ((((ks << 2) | hi) ^ bxor) << 3));
            acc[ct] = __builtin_amdgcn_mfma_f32_16x16x32_bf16(a, b, acc[ct], 0, 0, 0);
        }
    }
    __syncthreads();   // all waves done reading Bs; safe to reuse

    const int rloc = wave * 16 + (hi << 2);
    unsigned short* OutS = Bs + 40960;
    unsigned short* Ccg = Cc + (size_t)g * F * NG + rt * 128 + rloc;
    #pragma unroll
    for (int ct = 0; ct < 8; ++ct) {
        int col = ct * 16 + l15;
        uint2 w;
        w.x = pack16(acc[ct][0], acc[ct][1]);
        w.y = pack16(acc[ct][2], acc[ct][3]);
        *(uint2*)(Ccg + (size_t)col * NG) = w;
        #pragma unroll
        for (int r = 0; r < 4; ++r)
            OutS[(rloc + r) * F + col] = f2bf(acc[ct][r]);
    }
    __syncthreads();
    uint4* o4 = (uint4*)(Cr + ((size_t)g * NG + rt * 128) * F);
    const uint4* s4 = (const uint4*)OutS;
    #pragma unroll
    for (int u = tid; u < 128 * F / 8; u += 512) o4[u] = s4[u];
}

// ---------------- fused: t2 = S@Bc (LDS-staged B) -> t2 tile in LDS -> conv ----------------
// WRITE_H=1: h -> Hr (row) + Hc (col). WRITE_H=0: column max -> atomicMax(pooled).

template <int WRITE_H>
__global__ __launch_bounds__(512) void fused_conv_kernel(
    const unsigned short* __restrict__ S, const unsigned short* __restrict__ Bc,
    const unsigned short* __restrict__ A0, const unsigned short* __restrict__ A1,
    const unsigned short* __restrict__ Wswz, const float* __restrict__ bias,
    unsigned short* __restrict__ Hr, unsigned short* __restrict__ Hc,
    float* __restrict__ pooled) {
    __shared__ unsigned short Bs[65536];   // 128 KB; B stage -> t2 tile [128][136] -> epilogue
    const int g = blockIdx.x >> 2, rt = blockIdx.x & 3;
    const int tid = threadIdx.x, wave = tid >> 6, lane = tid & 63;
    const int l15 = lane & 15, hi = lane >> 4;
    const int lrow = wave * 16 + l15;

    const unsigned short* Bcg = Bc + (size_t)g * F * NG;
    #pragma unroll
    for (int it = 0; it < 16; ++it) {
        int u = it * 512 + tid;
        int f = u >> 6, c = u & 63;
        *(uint4*)(Bs + f * 512 + ((c ^ (f & 7)) << 3)) =
            *(const uint4*)(Bcg + (size_t)f * NG + (c << 3));
    }
    __syncthreads();

    // ---- S-phase: t2 tile = S(rows) @ B ----
    f32x4 sacc[8];
    #pragma unroll
    for (int ct = 0; ct < 8; ++ct) sacc[ct] = (f32x4){0.f, 0.f, 0.f, 0.f};
    {
        const unsigned short* Sg = S + ((size_t)g * NG + rt * 128 + lrow) * NG;
        const int bxor = l15 & 7;
        #pragma unroll 4
        for (int ks = 0; ks < 16; ++ks) {
            s16x8 a = *(const s16x8*)(Sg + ks * 32 + hi * 8);
            #pragma unroll
            for (int ct = 0; ct < 8; ++ct) {
                int col = ct * 16 + l15;
                s16x8 b = *(const s16x8*)(Bs + col * 512 + ((((ks << 2) | hi) ^ bxor) << 3));
                sacc[ct] = __builtin_amdgcn_mfma_f32_16x16x32_bf16(a, b, sacc[ct], 0, 0, 0);
            }
        }
    }
    __syncthreads();   // B reads complete; reuse Bs[0..17407] as t2 tile [128][136]

    {
        int rloc = wave * 16 + (hi << 2);
        #pragma unroll
        for (int ct = 0; ct < 8; ++ct) {
            int col = ct * 16 + l15;
            #pragma unroll
            for (int r = 0; r < 4; ++r)
                Bs[(rloc + r) * 136 + col] = f2bf(sacc[ct][r]);
        }
    }
    __syncthreads();

    // ---- conv phase: h = A0@W0 + A1@W1 + t2@W2 ----
    f32x4 acc[8];
    #pragma unroll
    for (int ct = 0; ct < 8; ++ct) acc[ct] = (f32x4){0.f, 0.f, 0.f, 0.f};
    const int arow = blockIdx.x * 128 + lrow;
    #pragma unroll
    for (int ks = 0; ks < 12; ++ks) {
        s16x8 a;
        if (ks < 8) {
            const unsigned short* Ab = (ks < 4) ? A0 : A1;
            a = *(const s16x8*)(Ab + (size_t)arow * F + (ks & 3) * 32 + hi * 8);
        } else {
            a = *(const s16x8*)(Bs + lrow * 136 + (ks - 8) * 32 + hi * 8);
        }
        const unsigned short* wb = Wswz + ((size_t)ks * 512 + lane) * 8;
        #pragma unroll
        for (int ct = 0; ct < 8; ++ct) {
            s16x8 b = *(const s16x8*)(wb + (size_t)ct * 512);
            acc[ct] = __builtin_amdgcn_mfma_f32_16x16x32_bf16(a, b, acc[ct], 0, 0, 0);
        }
    }

    const int rloc = wave * 16 + (hi << 2);
    if (WRITE_H) {
        unsigned short* OutS = Bs + 40960;   // disjoint from t2 tile; no barrier needed
        #pragma unroll
        for (int ct = 0; ct < 8; ++ct) {
            int col = ct * 16 + l15;
            float b = bias[col];
            float v0 = fmaxf(acc[ct][0] + b, 0.f);
            float v1 = fmaxf(acc[ct][1] + b, 0.f);
            float v2 = fmaxf(acc[ct][2] + b, 0.f);
            float v3 = fmaxf(acc[ct][3] + b, 0.f);
            uint2 w;
            w.x = pack16(v0, v1);
            w.y = pack16(v2, v3);
            *(uint2*)(Hc + (size_t)g * F * NG + (size_t)col * NG + rt * 128 + rloc) = w;
            OutS[(rloc + 0) * F + col] = f2bf(v0);
            OutS[(rloc + 1) * F + col] = f2bf(v1);
            OutS[(rloc + 2) * F + col] = f2bf(v2);
            OutS[(rloc + 3) * F + col] = f2bf(v3);
        }
        __syncthreads();
        uint4* o4 = (uint4*)(Hr + (size_t)blockIdx.x * 128 * F);
        const uint4* s4 = (const uint4*)OutS;
        #pragma unroll
        for (int u = tid; u < 128 * F / 8; u += 512) o4[u] = s4[u];
    } else {
        __syncthreads();   // t2-tile reads done before aliasing with wmax
        float* wmax = (float*)Bs;
        #pragma unroll
        for (int ct = 0; ct < 8; ++ct) {
            int col = ct * 16 + l15;
            float b = bias[col];
            float m = fmaxf(fmaxf(acc[ct][0], acc[ct][1]), fmaxf(acc[ct][2], acc[ct][3]));
            m = fmaxf(m + b, 0.f);
            m = fmaxf(m, __shfl_xor(m, 16));
            m = fmaxf(m, __shfl_xor(m, 32));
            if (lane < 16) wmax[wave * F + col] = m;
        }
        __syncthreads();
        if (tid < F) {
            float m = wmax[tid];
            #pragma unroll
            for (int w = 1; w < 8; ++w) m = fmaxf(m, wmax[w * F + tid]);
            atomicMax((unsigned int*)(pooled + (size_t)g * F + tid), __float_as_uint(m));
        }
    }
}

// ---------------- output head: out = pooled @ Wout + bout (f32) ----------------

__global__ __launch_bounds__(64) void out_gemm_kernel(const float* __restrict__ pooled,
                                                      const float* __restrict__ Wout,
                                                      const float* __restrict__ bout,
                                                      float* __restrict__ out) {
    __shared__ float p[F];
    int b = blockIdx.x, g = threadIdx.x;
    p[g] = pooled[(size_t)b * F + g];
    p[g + 64] = pooled[(size_t)b * F + g + 64];
    __syncthreads();
    float acc = bout[g];
    #pragma unroll 8
    for (int k = 0; k < F; ++k) acc += p[k] * Wout[k * 64 + g];
    out[(size_t)b * 64 + g] = acc;
}

// ---------------- launch ----------------

extern "C" void kernel_launch(void* const* d_in, const int* in_sizes, int n_in,
                              void* d_out, int out_size, void* d_ws, size_t ws_size,
                              hipStream_t stream) {
    const float* X     = (const float*)d_in[0];
    const int*   ei    = (const int*)d_in[2];
    const float* W1    = (const float*)d_in[3];
    const float* b1    = (const float*)d_in[4];
    const float* W2    = (const float*)d_in[5];
    const float* b2    = (const float*)d_in[6];
    const float* Wout  = (const float*)d_in[7];
    const float* bout  = (const float*)d_in[8];
    const float* alpha = (const float*)d_in[9];

    const int N = in_sizes[0] / F;   // 32768
    const int E = in_sizes[2] / 2;   // 524288
    const int Bg = N / NG;           // 64

    const int* srcv = ei;
    const int* dstv = ei + E;

    char* ws = (char*)d_ws;
    const size_t SBYTES = (size_t)Bg * NG * NG * 2;   // 33.55 MB
    const size_t PBYTES = (size_t)N * F * 2;          // 8.39 MB each

    unsigned short* Sb = (unsigned short*)ws;
    unsigned short* P0 = (unsigned short*)(ws + SBYTES);               // Xr -> h1r
    unsigned short* P1 = (unsigned short*)(ws + SBYTES + PBYTES);      // Xc -> h1c
    unsigned short* P2 = (unsigned short*)(ws + SBYTES + 2 * PBYTES);  // t1r / u1r
    unsigned short* P3 = (unsigned short*)(ws + SBYTES + 3 * PBYTES);  // t1c / u1c
    char* tail = ws + SBYTES + 4 * PBYTES;
    unsigned short* Wswz1 = (unsigned short*)tail;
    unsigned short* Wswz2 = Wswz1 + (size_t)3 * F * F;
    float* pooled = (float*)(Wswz2 + (size_t)3 * F * F);
    // cnt aliases P2+P3 (exactly 16.78 MB); consumed by sgen before sapply writes P2/P3
    unsigned int* cnt32 = (unsigned int*)P2;

    // prep
    cast_kernel<<<Bg * 8, 256, 0, stream>>>(X, P0, P1);
    wprep_kernel<<<384, 256, 0, stream>>>(W1, W2, Wswz1, Wswz2);

    // dense S build + pooled init (relu >= 0, so 0 is a valid max identity)
    hipMemsetAsync(cnt32, 0, (size_t)Bg * NG * NG, stream);
    hipMemsetAsync(pooled, 0, (size_t)Bg * F * 4, stream);
    cnt_scatter_kernel<<<(E + 255) / 256, 256, 0, stream>>>(srcv, dstv, cnt32, E);
    sgen_kernel<<<(Bg * NG * NG / 8) / 256, 256, 0, stream>>>((const unsigned char*)cnt32, Sb, alpha);

    // layer 1: t1 = S@X; h1 = relu(X@W0 + t1@W1 + (S@t1)@W2 + b1)
    sapply_kernel<<<Bg * 4, 512, 0, stream>>>(Sb, P1, P2, P3);
    fused_conv_kernel<1><<<Bg * 4, 512, 0, stream>>>(Sb, P3, P0, P2, Wswz1, b1, P0, P1, nullptr);

    // layer 2: u1 = S@h1; pooled = colmax(relu(h1@W0 + u1@W1 + (S@u1)@W2 + b2))
    sapply_kernel<<<Bg * 4, 512, 0, stream>>>(Sb, P1, P2, P3);
    fused_conv_kernel<0><<<Bg * 4, 512, 0, stream>>>(Sb, P3, P0, P2, Wswz2, b2, nullptr, nullptr, pooled);

    // head
    out_gemm_kernel<<<Bg, 64, 0, stream>>>(pooled, Wout, bout, (float*)d_out);
}